// Round 17
// baseline (69.372 us; speedup 1.0000x reference)
//
#include <hip/hip_runtime.h>
#include <hip/hip_bf16.h>
#include <stddef.h>

#define R_ 4
#define J_ 6
#define N_ 4096
#define DI_ 128
#define DO_ 64

typedef __bf16 bf16x8 __attribute__((ext_vector_type(8)));
typedef __bf16 bf16x4 __attribute__((ext_vector_type(4)));
typedef float f32x4 __attribute__((ext_vector_type(4)));

static __device__ __forceinline__ bf16x8 cvt8(f32x4 a, f32x4 b) {
    bf16x8 r;
    r[0] = (__bf16)a[0]; r[1] = (__bf16)a[1]; r[2] = (__bf16)a[2]; r[3] = (__bf16)a[3];
    r[4] = (__bf16)b[0]; r[5] = (__bf16)b[1]; r[6] = (__bf16)b[2]; r[7] = (__bf16)b[3];
    return r;
}

// ---------------------------------------------------------------------------
// Kernel 1: r13 k_prep verbatim (256 blocks — r16 showed 512 is not better).
// y as pre-packed MFMA B-fragments:
//   Yf[r][kb=m>>5][ot=o>>4][lane=(o&15)+16*((m&31)>>3)][j=m&7]   (bf16)
// ---------------------------------------------------------------------------
__global__ __launch_bounds__(256) void k_prep(const float* __restrict__ theta,
                                              const float* __restrict__ tt,
                                              const float* __restrict__ x,
                                              const float* __restrict__ fcw,
                                              __bf16* __restrict__ Yf)
{
    const int b = blockIdx.x;
    const int r = b >> 6;
    const int m0 = (b & 63) << 6;
    const int tid = threadIdx.x;
    const int w = tid >> 6, l = tid & 63, lg = l >> 4, lr = l & 15;

    float coef = 0.f;
    #pragma unroll
    for (int j = 0; j < J_; ++j) coef += theta[r * J_ + j] * tt[r * J_ + j];

    const float* wp  = fcw + ((size_t)r * DO_ + w * 16 + lr) * DI_ + lg * 8;
    const float* xp0 = x   + ((size_t)r * N_  + m0     + lr) * DI_ + lg * 8;

    f32x4 acc[4];
    #pragma unroll
    for (int mt = 0; mt < 4; ++mt) acc[mt] = (f32x4)0.0f;

    #pragma unroll
    for (int s = 0; s < 4; ++s) {
        bf16x8 af = cvt8(*(const f32x4*)(wp + s * 32), *(const f32x4*)(wp + s * 32 + 4));
        #pragma unroll
        for (int mt = 0; mt < 4; ++mt) {
            const float* xp = xp0 + (size_t)mt * 16 * DI_ + s * 32;
            bf16x8 bf = cvt8(*(const f32x4*)xp, *(const f32x4*)(xp + 4));
            acc[mt] = __builtin_amdgcn_mfma_f32_16x16x32_bf16(af, bf, acc[mt], 0, 0, 0);
        }
    }

    __shared__ __bf16 ybuf[2][4][64][8];
    #pragma unroll
    for (int mt = 0; mt < 4; ++mt) {
        const int kb2 = mt >> 1;
        const int hi  = ((mt & 1) << 1) + (lr >> 3);
        const int j   = lr & 7;
        #pragma unroll
        for (int i = 0; i < 4; ++i)
            ybuf[kb2][w][lg * 4 + i + (hi << 4)][j] = (__bf16)(coef * acc[mt][i]);
    }
    __syncthreads();

    const __bf16* yb = &ybuf[0][0][0][0];
    __bf16* dst = Yf + (size_t)r * (DO_ * N_) + (size_t)(m0 >> 5) * 2048;
    *(bf16x8*)(dst + tid * 8)        = *(const bf16x8*)(yb + tid * 8);
    *(bf16x8*)(dst + 2048 + tid * 8) = *(const bf16x8*)(yb + 2048 + tid * 8);
}

// ---------------------------------------------------------------------------
// Kernel 2 (FUSED diff+conv): block = one 16-row n-tile x ALL 4 relations.
// 8 waves = (r = w>>1, oh = w&1): BM=16 rows of relation r, FULL K, 2 o-tiles
// (o = oh*32..+31). No kh-split -> no red buffer. After the K-loop, u for all
// 4 r of these rows sits in 17KB LDS -> the 1x1 relation conv + prelu(p1) is
// computed in-block; k_conv and its launch gap are eliminated.
// All mechanisms proven: 4-row x 256B staging + (row&7)<<4 involution (both
// sides), Y register double-buffer (4 frags), LDS-only barrier, r13 prefetch
// distances. LDS 16+17.4KB -> 2 blocks/CU; ~100 VGPR (< 128 cliff).
// u accumulation K-order unchanged -> absmax 1.0; h = k_conv's exact formula.
// ---------------------------------------------------------------------------
__global__ __launch_bounds__(512, 2) void k_fused(const float* __restrict__ A,
                                                  const __bf16* __restrict__ Yf,
                                                  const float* __restrict__ fcb,
                                                  const float* __restrict__ cw,
                                                  const float* __restrict__ cb,
                                                  const float* __restrict__ p0p,
                                                  const float* __restrict__ p1p,
                                                  float* __restrict__ U,
                                                  float* __restrict__ H)
{
    const int b = blockIdx.x;             // 256 blocks = 256 n-tiles
    const int n0 = b << 4;
    const int tid = threadIdx.x;
    const int w = tid >> 6, l = tid & 63, lg = l >> 4, lr = l & 15;
    const int r = w >> 1, oh = w & 1;

    __shared__ __bf16 abuf[4][2][16 * 64];          // [r][parity][row][k] 16KB
    __shared__ __align__(16) float ubuf[4][16][68]; // u staging, 17.4KB

    const int srow = l >> 4;
    const int scol = (l & 15) * 4;
    // wave (r, oh) stages rows oh*8 + 4j + srow (j=0,1) of its relation
    const float* Abl = A + ((size_t)r * N_ + n0 + oh * 8 + srow) * N_ + scol;

    int wo[2];
    #pragma unroll
    for (int j = 0; j < 2; ++j) {
        const int row = oh * 8 + 4 * j + srow;
        wo[j] = row * 64 + (((scol * 2) ^ ((row & 7) << 4)) >> 1);
    }

    const int q = (lr & 7) << 4;
    int ro[2];
    #pragma unroll
    for (int ss = 0; ss < 2; ++ss)
        ro[ss] = lr * 64 + (((ss * 64 + lg * 16) ^ q) >> 1);

    // Y frag (kb, t): yb0 + kb*2048 + t*512   (this wave's ot = oh*2 + t)
    const __bf16* yb0 = Yf + (size_t)r * (DO_ * N_) + (size_t)(oh * 2) * 512
                           + (size_t)l * 8;

    f32x4 acc[2];
    acc[0] = (f32x4)0.0f; acc[1] = (f32x4)0.0f;

#define LOADRG(dst, c) {                                                   \
        _Pragma("unroll")                                                  \
        for (int j = 0; j < 2; ++j)                                        \
            dst[j] = *(const f32x4*)(Abl + (size_t)(4 * j) * N_ + (c) * 64); \
    }
#define YLOAD(dst, c) {                                                    \
        _Pragma("unroll")                                                  \
        for (int ss = 0; ss < 2; ++ss)                                     \
            _Pragma("unroll")                                              \
            for (int t = 0; t < 2; ++t)                                    \
                dst[ss * 2 + t] = *(const bf16x8*)(yb0                     \
                    + (size_t)((c) * 2 + ss) * 2048 + t * 512);            \
    }
#define STAGE(src, par) {                                                  \
        __bf16* ab = &abuf[r][par][0];                                     \
        _Pragma("unroll")                                                  \
        for (int j = 0; j < 2; ++j) {                                      \
            bf16x4 cv;                                                     \
            cv[0] = (__bf16)src[j][0]; cv[1] = (__bf16)src[j][1];          \
            cv[2] = (__bf16)src[j][2]; cv[3] = (__bf16)src[j][3];          \
            *(bf16x4*)&ab[wo[j]] = cv;                                     \
        }                                                                  \
    }
#define BODY(yfr, par) {                                                   \
        const __bf16* abr = &abuf[r][par][0];                              \
        _Pragma("unroll")                                                  \
        for (int ss = 0; ss < 2; ++ss) {                                   \
            bf16x8 af = *(const bf16x8*)&abr[ro[ss]];                      \
            _Pragma("unroll")                                              \
            for (int t = 0; t < 2; ++t)                                    \
                acc[t] = __builtin_amdgcn_mfma_f32_16x16x32_bf16(af, yfr[ss * 2 + t], acc[t], 0, 0, 0); \
        }                                                                  \
    }
#define LDSBAR() {                                                         \
        asm volatile("s_waitcnt lgkmcnt(0)" ::: "memory");                 \
        __builtin_amdgcn_s_barrier();                                      \
        __builtin_amdgcn_sched_barrier(0);                                 \
    }

    f32x4 rgA[2], rgB[2];
    bf16x8 yA[4], yB[4];
    LOADRG(rgA, 0);
    LOADRG(rgB, 1);
    YLOAD(yA, 0);

    for (int c = 0; c < 64; c += 2) {
        STAGE(rgA, 0);
        if (c + 2 < 64) LOADRG(rgA, c + 2);
        YLOAD(yB, c + 1);
        LDSBAR();
        BODY(yA, 0);
        STAGE(rgB, 1);
        if (c + 3 < 64) LOADRG(rgB, c + 3);
        if (c + 2 < 64) YLOAD(yA, c + 2);
        LDSBAR();
        BODY(yB, 1);
    }

#undef LOADRG
#undef YLOAD
#undef STAGE
#undef BODY
#undef LDSBAR

    // u = prelu(acc + fcb) -> ubuf  (D layout: n-row = lg*4+i, o-col = lr)
    const float p0 = *p0p;
    #pragma unroll
    for (int t = 0; t < 2; ++t) {
        const int o = (oh * 2 + t) * 16 + lr;
        const float bias = fcb[r * DO_ + o];
        #pragma unroll
        for (int i = 0; i < 4; ++i) {
            float v = acc[t][i] + bias;
            ubuf[r][lg * 4 + i][o] = v >= 0.f ? v : p0 * v;
        }
    }
    __syncthreads();

    // conv phase: 256 threads, one (n, o-quad) cell each, all 4 r/q
    if (tid < 256) {
        const int n  = tid >> 4;
        const int ob = (tid & 15) * 4;
        f32x4 u0 = *(const f32x4*)&ubuf[0][n][ob];
        f32x4 u1 = *(const f32x4*)&ubuf[1][n][ob];
        f32x4 u2 = *(const f32x4*)&ubuf[2][n][ob];
        f32x4 u3 = *(const f32x4*)&ubuf[3][n][ob];

        *(f32x4*)&U[((size_t)0 * N_ + n0 + n) * DO_ + ob] = u0;
        *(f32x4*)&U[((size_t)1 * N_ + n0 + n) * DO_ + ob] = u1;
        *(f32x4*)&U[((size_t)2 * N_ + n0 + n) * DO_ + ob] = u2;
        *(f32x4*)&U[((size_t)3 * N_ + n0 + n) * DO_ + ob] = u3;

        const float p1 = *p1p;
        const size_t SL = (size_t)N_ * DO_;
        #pragma unroll
        for (int qq = 0; qq < 4; ++qq) {
            f32x4 hv = cw[qq * 4 + 0] * u0 + cw[qq * 4 + 1] * u1 +
                       cw[qq * 4 + 2] * u2 + cw[qq * 4 + 3] * u3;
            const float bq = cb[qq];
            f32x4 ho;
            #pragma unroll
            for (int j = 0; j < 4; ++j) {
                const float v = hv[j] + bq;
                ho[j] = v >= 0.f ? v : p1 * v;
            }
            *(f32x4*)&H[qq * SL + (size_t)(n0 + n) * DO_ + ob] = ho;
        }
    }
}

extern "C" void kernel_launch(void* const* d_in, const int* in_sizes, int n_in,
                              void* d_out, int out_size, void* d_ws, size_t ws_size,
                              hipStream_t stream)
{
    const float* theta = (const float*)d_in[0];
    const float* tt    = (const float*)d_in[1];
    const float* a     = (const float*)d_in[2];
    const float* x     = (const float*)d_in[3];
    const float* fcw   = (const float*)d_in[4];
    const float* fcb   = (const float*)d_in[5];
    const float* cw    = (const float*)d_in[6];
    const float* cb    = (const float*)d_in[7];
    const float* p0    = (const float*)d_in[8];
    const float* p1    = (const float*)d_in[9];

    float* out = (float*)d_out;
    float* H = out;                              // output 0: h  [R,N,DO]
    float* U = out + (size_t)R_ * N_ * DO_;      // output 1: u  [R,N,DO]

    // Y lives in d_ws (2 MB; harness provides ~1 GB). H-region fallback is
    // NOT safe with the fused kernel (it reads Y while writing H), so d_ws
    // is used unconditionally here.
    __bf16* Y = (__bf16*)d_ws;

    k_prep<<<dim3(256), dim3(256), 0, stream>>>(theta, tt, x, fcw, Y);
    k_fused<<<dim3(256), dim3(512), 0, stream>>>(a, Y, fcb, cw, cb, p0, p1, U, H);
}

// Round 18
// 61.063 us; speedup vs baseline: 1.1361x; 1.1361x over previous
//
#include <hip/hip_runtime.h>
#include <hip/hip_bf16.h>
#include <stddef.h>

#define R_ 4
#define J_ 6
#define N_ 4096
#define DI_ 128
#define DO_ 64

typedef __bf16 bf16x8 __attribute__((ext_vector_type(8)));
typedef __bf16 bf16x4 __attribute__((ext_vector_type(4)));
typedef float f32x4 __attribute__((ext_vector_type(4)));

static __device__ __forceinline__ bf16x8 cvt8(f32x4 a, f32x4 b) {
    bf16x8 r;
    r[0] = (__bf16)a[0]; r[1] = (__bf16)a[1]; r[2] = (__bf16)a[2]; r[3] = (__bf16)a[3];
    r[4] = (__bf16)b[0]; r[5] = (__bf16)b[1]; r[6] = (__bf16)b[2]; r[7] = (__bf16)b[3];
    return r;
}

// ---------------------------------------------------------------------------
// Kernel 1: r13 k_prep verbatim. y as pre-packed MFMA B-fragments:
//   Yf[r][kb=m>>5][ot=o>>4][lane=(o&15)+16*((m&31)>>3)][j=m&7]   (bf16)
// ---------------------------------------------------------------------------
__global__ __launch_bounds__(256) void k_prep(const float* __restrict__ theta,
                                              const float* __restrict__ tt,
                                              const float* __restrict__ x,
                                              const float* __restrict__ fcw,
                                              __bf16* __restrict__ Yf)
{
    const int b = blockIdx.x;
    const int r = b >> 6;
    const int m0 = (b & 63) << 6;
    const int tid = threadIdx.x;
    const int w = tid >> 6, l = tid & 63, lg = l >> 4, lr = l & 15;

    float coef = 0.f;
    #pragma unroll
    for (int j = 0; j < J_; ++j) coef += theta[r * J_ + j] * tt[r * J_ + j];

    const float* wp  = fcw + ((size_t)r * DO_ + w * 16 + lr) * DI_ + lg * 8;
    const float* xp0 = x   + ((size_t)r * N_  + m0     + lr) * DI_ + lg * 8;

    f32x4 acc[4];
    #pragma unroll
    for (int mt = 0; mt < 4; ++mt) acc[mt] = (f32x4)0.0f;

    #pragma unroll
    for (int s = 0; s < 4; ++s) {
        bf16x8 af = cvt8(*(const f32x4*)(wp + s * 32), *(const f32x4*)(wp + s * 32 + 4));
        #pragma unroll
        for (int mt = 0; mt < 4; ++mt) {
            const float* xp = xp0 + (size_t)mt * 16 * DI_ + s * 32;
            bf16x8 bf = cvt8(*(const f32x4*)xp, *(const f32x4*)(xp + 4));
            acc[mt] = __builtin_amdgcn_mfma_f32_16x16x32_bf16(af, bf, acc[mt], 0, 0, 0);
        }
    }

    __shared__ __bf16 ybuf[2][4][64][8];
    #pragma unroll
    for (int mt = 0; mt < 4; ++mt) {
        const int kb2 = mt >> 1;
        const int hi  = ((mt & 1) << 1) + (lr >> 3);
        const int j   = lr & 7;
        #pragma unroll
        for (int i = 0; i < 4; ++i)
            ybuf[kb2][w][lg * 4 + i + (hi << 4)][j] = (__bf16)(coef * acc[mt][i]);
    }
    __syncthreads();

    const __bf16* yb = &ybuf[0][0][0][0];
    __bf16* dst = Yf + (size_t)r * (DO_ * N_) + (size_t)(m0 >> 5) * 2048;
    *(bf16x8*)(dst + tid * 8)        = *(const bf16x8*)(yb + tid * 8);
    *(bf16x8*)(dst + 2048 + tid * 8) = *(const bf16x8*)(yb + 2048 + tid * 8);
}

// ---------------------------------------------------------------------------
// Kernel 2: r13 schedule at BM=32 -> grid 512 -> 16 waves/CU (2 blocks/CU).
// ONE mechanism changed vs r13: thread-level parallelism doubled (2->4
// waves/SIMD) to cover the ~600cy/chunk exposed memory latency that per-wave
// prefetch depth could not. All else verbatim: 8 waves = kh x ot, 4-row x
// 256B A staging + (row&7)<<4 involution both sides, Y register
// double-buffer, LDS-only barrier, same K-split -> bit-identical, absmax 1.0.
// LDS 16KB abuf + 20KB red = 36KB; VGPR ~60 (capped 128 via bounds(512,4)).
// ---------------------------------------------------------------------------
__global__ __launch_bounds__(512, 4) void k_diff(const float* __restrict__ A,
                                                 const __bf16* __restrict__ Yf,
                                                 const float* __restrict__ fcb,
                                                 const float* __restrict__ p0p,
                                                 float* __restrict__ U)
{
    const int b = blockIdx.x;
    const int r = b >> 7;
    const int n0 = (b & 127) << 5;
    const int tid = threadIdx.x;
    const int w = tid >> 6, l = tid & 63, lg = l >> 4, lr = l & 15;
    const int kh = w >> 2, ot = w & 3;

    __shared__ __bf16 abuf[2][2][32 * 64];           // [kh][parity][row][k] 16KB
    __shared__ __align__(16) float red[8][32][20];   // 20KB

    const int srow = l >> 4;
    const int scol = (l & 15) * 4;
    // wave (kh, ot) stages rows ot*8 + 4j + srow (j=0,1) of its kh chunk
    const float* Abl = A + ((size_t)r * N_ + n0 + ot * 8 + srow) * N_
                         + (size_t)kh * 2048 + scol;

    int wo[2];
    #pragma unroll
    for (int j = 0; j < 2; ++j) {
        const int row = ot * 8 + 4 * j + srow;
        wo[j] = row * 64 + (((scol * 2) ^ ((row & 7) << 4)) >> 1);
    }

    const int q = (lr & 7) << 4;
    int ro[2][2];
    #pragma unroll
    for (int mt = 0; mt < 2; ++mt)
        #pragma unroll
        for (int ss = 0; ss < 2; ++ss)
            ro[mt][ss] = (mt * 16 + lr) * 64 + (((ss * 64 + lg * 16) ^ q) >> 1);

    const __bf16* yb0 = Yf + (size_t)r * (DO_ * N_) + (size_t)kh * 64 * 2048
                           + (size_t)ot * 512 + (size_t)l * 8;

    f32x4 acc[2];
    acc[0] = (f32x4)0.0f; acc[1] = (f32x4)0.0f;

#define LOADRG(dst, c) {                                                   \
        _Pragma("unroll")                                                  \
        for (int j = 0; j < 2; ++j)                                        \
            dst[j] = *(const f32x4*)(Abl + (size_t)(4 * j) * N_ + (c) * 64); \
    }
#define YLOAD(dst, c) {                                                    \
        dst[0] = *(const bf16x8*)(yb0 + (size_t)((c) * 2 + 0) * 2048);     \
        dst[1] = *(const bf16x8*)(yb0 + (size_t)((c) * 2 + 1) * 2048);     \
    }
#define STAGE(src, par) {                                                  \
        __bf16* ab = &abuf[kh][par][0];                                    \
        _Pragma("unroll")                                                  \
        for (int j = 0; j < 2; ++j) {                                      \
            bf16x4 cv;                                                     \
            cv[0] = (__bf16)src[j][0]; cv[1] = (__bf16)src[j][1];          \
            cv[2] = (__bf16)src[j][2]; cv[3] = (__bf16)src[j][3];          \
            *(bf16x4*)&ab[wo[j]] = cv;                                     \
        }                                                                  \
    }
#define BODY(yfr, par) {                                                   \
        const __bf16* abr = &abuf[kh][par][0];                             \
        _Pragma("unroll")                                                  \
        for (int ss = 0; ss < 2; ++ss) {                                   \
            _Pragma("unroll")                                              \
            for (int mt = 0; mt < 2; ++mt) {                               \
                bf16x8 af = *(const bf16x8*)&abr[ro[mt][ss]];              \
                acc[mt] = __builtin_amdgcn_mfma_f32_16x16x32_bf16(af, yfr[ss], acc[mt], 0, 0, 0); \
            }                                                              \
        }                                                                  \
    }
#define LDSBAR() {                                                         \
        asm volatile("s_waitcnt lgkmcnt(0)" ::: "memory");                 \
        __builtin_amdgcn_s_barrier();                                      \
        __builtin_amdgcn_sched_barrier(0);                                 \
    }

    f32x4 rgA[2], rgB[2];
    bf16x8 yA[2], yB[2];
    LOADRG(rgA, 0);
    LOADRG(rgB, 1);
    YLOAD(yA, 0);

    for (int c = 0; c < 32; c += 2) {
        STAGE(rgA, 0);
        if (c + 2 < 32) LOADRG(rgA, c + 2);
        YLOAD(yB, c + 1);
        LDSBAR();
        BODY(yA, 0);
        STAGE(rgB, 1);
        if (c + 3 < 32) LOADRG(rgB, c + 3);
        if (c + 2 < 32) YLOAD(yA, c + 2);
        LDSBAR();
        BODY(yB, 1);
    }

#undef LOADRG
#undef YLOAD
#undef STAGE
#undef BODY
#undef LDSBAR

    #pragma unroll
    for (int mt = 0; mt < 2; ++mt)
        #pragma unroll
        for (int i = 0; i < 4; ++i)
            red[w][mt * 16 + lg * 4 + i][lr] = acc[mt][i];
    __syncthreads();

    const float p0 = *p0p;
    {
        const int idx = tid;                 // 512 threads = 32 n x 16 oq
        const int n  = idx >> 4;
        const int oq = idx & 15;
        const int t2 = oq >> 2;
        const int oo = (oq & 3) * 4;
        f32x4 s4 = *(const f32x4*)&red[t2][n][oo] + *(const f32x4*)&red[t2 + 4][n][oo];
        const int o = t2 * 16 + oo;
        f32x4 uv;
        #pragma unroll
        for (int j = 0; j < 4; ++j) {
            const float v = s4[j] + fcb[r * DO_ + o + j];
            uv[j] = v >= 0.f ? v : p0 * v;
        }
        *(f32x4*)&U[((size_t)r * N_ + n0 + n) * DO_ + o] = uv;
    }
}

// ---------------------------------------------------------------------------
// Kernel 3 (unchanged): h = prelu(conv_w @ u + conv_b)
// ---------------------------------------------------------------------------
__global__ __launch_bounds__(256) void k_conv(const float* __restrict__ U,
                                              const float* __restrict__ cw,
                                              const float* __restrict__ cb,
                                              const float* __restrict__ p1p,
                                              float* __restrict__ H)
{
    const size_t t = (size_t)blockIdx.x * 256 + threadIdx.x;
    const size_t base = t * 4;
    const size_t SL = (size_t)N_ * DO_;  // 262144

    f32x4 u0 = *(const f32x4*)&U[base];
    f32x4 u1 = *(const f32x4*)&U[base + SL];
    f32x4 u2 = *(const f32x4*)&U[base + 2 * SL];
    f32x4 u3 = *(const f32x4*)&U[base + 3 * SL];
    const float p1 = *p1p;

    #pragma unroll
    for (int qq = 0; qq < 4; ++qq) {
        f32x4 hv = cw[qq * 4 + 0] * u0 + cw[qq * 4 + 1] * u1 +
                   cw[qq * 4 + 2] * u2 + cw[qq * 4 + 3] * u3;
        const float bq = cb[qq];
        f32x4 ho;
        #pragma unroll
        for (int j = 0; j < 4; ++j) {
            const float v = hv[j] + bq;
            ho[j] = v >= 0.f ? v : p1 * v;
        }
        *(f32x4*)&H[qq * SL + base] = ho;
    }
}

extern "C" void kernel_launch(void* const* d_in, const int* in_sizes, int n_in,
                              void* d_out, int out_size, void* d_ws, size_t ws_size,
                              hipStream_t stream)
{
    const float* theta = (const float*)d_in[0];
    const float* tt    = (const float*)d_in[1];
    const float* a     = (const float*)d_in[2];
    const float* x     = (const float*)d_in[3];
    const float* fcw   = (const float*)d_in[4];
    const float* fcb   = (const float*)d_in[5];
    const float* cw    = (const float*)d_in[6];
    const float* cb    = (const float*)d_in[7];
    const float* p0    = (const float*)d_in[8];
    const float* p1    = (const float*)d_in[9];

    float* out = (float*)d_out;
    float* H = out;                              // output 0: h  [R,N,DO]
    float* U = out + (size_t)R_ * N_ * DO_;      // output 1: u  [R,N,DO]

    const size_t ybytes = (size_t)R_ * DO_ * N_ * sizeof(__bf16);
    __bf16* Y = (ws_size >= ybytes) ? (__bf16*)d_ws : (__bf16*)H;

    k_prep<<<dim3(256), dim3(256), 0, stream>>>(theta, tt, x, fcw, Y);
    k_diff<<<dim3(512), dim3(512), 0, stream>>>(a, Y, fcb, p0, U);
    k_conv<<<dim3(256), dim3(256), 0, stream>>>(U, cw, cb, p1, H);
}

// Round 19
// 58.955 us; speedup vs baseline: 1.1767x; 1.0358x over previous
//
#include <hip/hip_runtime.h>
#include <hip/hip_bf16.h>
#include <stddef.h>

#define R_ 4
#define J_ 6
#define N_ 4096
#define DI_ 128
#define DO_ 64

typedef __bf16 bf16x8 __attribute__((ext_vector_type(8)));
typedef __bf16 bf16x4 __attribute__((ext_vector_type(4)));
typedef float f32x4 __attribute__((ext_vector_type(4)));

static __device__ __forceinline__ bf16x8 cvt8(f32x4 a, f32x4 b) {
    bf16x8 r;
    r[0] = (__bf16)a[0]; r[1] = (__bf16)a[1]; r[2] = (__bf16)a[2]; r[3] = (__bf16)a[3];
    r[4] = (__bf16)b[0]; r[5] = (__bf16)b[1]; r[6] = (__bf16)b[2]; r[7] = (__bf16)b[3];
    return r;
}

// ---------------------------------------------------------------------------
// FINAL = r13 champion verbatim (best measured: 58.53 us, absmax 1.0).
// k_prep: y as pre-packed MFMA B-fragments
//   Yf[r][kb=m>>5][ot=o>>4][lane=(o&15)+16*((m&31)>>3)][j=m&7]   (bf16)
// ---------------------------------------------------------------------------
__global__ __launch_bounds__(256) void k_prep(const float* __restrict__ theta,
                                              const float* __restrict__ tt,
                                              const float* __restrict__ x,
                                              const float* __restrict__ fcw,
                                              __bf16* __restrict__ Yf)
{
    const int b = blockIdx.x;
    const int r = b >> 6;
    const int m0 = (b & 63) << 6;
    const int tid = threadIdx.x;
    const int w = tid >> 6, l = tid & 63, lg = l >> 4, lr = l & 15;

    float coef = 0.f;
    #pragma unroll
    for (int j = 0; j < J_; ++j) coef += theta[r * J_ + j] * tt[r * J_ + j];

    const float* wp  = fcw + ((size_t)r * DO_ + w * 16 + lr) * DI_ + lg * 8;
    const float* xp0 = x   + ((size_t)r * N_  + m0     + lr) * DI_ + lg * 8;

    f32x4 acc[4];
    #pragma unroll
    for (int mt = 0; mt < 4; ++mt) acc[mt] = (f32x4)0.0f;

    #pragma unroll
    for (int s = 0; s < 4; ++s) {
        bf16x8 af = cvt8(*(const f32x4*)(wp + s * 32), *(const f32x4*)(wp + s * 32 + 4));
        #pragma unroll
        for (int mt = 0; mt < 4; ++mt) {
            const float* xp = xp0 + (size_t)mt * 16 * DI_ + s * 32;
            bf16x8 bf = cvt8(*(const f32x4*)xp, *(const f32x4*)(xp + 4));
            acc[mt] = __builtin_amdgcn_mfma_f32_16x16x32_bf16(af, bf, acc[mt], 0, 0, 0);
        }
    }

    __shared__ __bf16 ybuf[2][4][64][8];
    #pragma unroll
    for (int mt = 0; mt < 4; ++mt) {
        const int kb2 = mt >> 1;
        const int hi  = ((mt & 1) << 1) + (lr >> 3);
        const int j   = lr & 7;
        #pragma unroll
        for (int i = 0; i < 4; ++i)
            ybuf[kb2][w][lg * 4 + i + (hi << 4)][j] = (__bf16)(coef * acc[mt][i]);
    }
    __syncthreads();

    const __bf16* yb = &ybuf[0][0][0][0];
    __bf16* dst = Yf + (size_t)r * (DO_ * N_) + (size_t)(m0 >> 5) * 2048;
    *(bf16x8*)(dst + tid * 8)        = *(const bf16x8*)(yb + tid * 8);
    *(bf16x8*)(dst + 2048 + tid * 8) = *(const bf16x8*)(yb + 2048 + tid * 8);
}

// ---------------------------------------------------------------------------
// k_diff (r13): BM=64, 8 waves = ot x kh, 2-parity dbuf swizzled LDS (72KB
// -> 2 blocks/CU), A depth-2 register prefetch, Y REGISTER DOUBLE-BUFFER
// (the one proven latency win: +2.6us), LDS-only barrier
// (lgkmcnt(0)+s_barrier keeps A-prefetch loads in flight), 2-way K reduce,
// fused bias+PReLU epilogue.
// ---------------------------------------------------------------------------
__global__ __launch_bounds__(512, 2) void k_diff(const float* __restrict__ A,
                                                 const __bf16* __restrict__ Yf,
                                                 const float* __restrict__ fcb,
                                                 const float* __restrict__ p0p,
                                                 float* __restrict__ U)
{
    const int b = blockIdx.x;
    const int r = b >> 6;
    const int n0 = (b & 63) << 6;
    const int tid = threadIdx.x;
    const int w = tid >> 6, l = tid & 63, lg = l >> 4, lr = l & 15;
    const int kh = w >> 2, ot = w & 3;

    __shared__ __bf16 abuf[2][2][64 * 64];           // [kh][parity][row][k] 32KB
    __shared__ __align__(16) float red[8][64][20];   // 40KB

    const int srow = l >> 4;
    const int scol = (l & 15) * 4;
    const float* Abl = A + ((size_t)r * N_ + n0 + ot * 16 + srow) * N_
                         + (size_t)kh * 2048 + scol;

    int wo[4];
    #pragma unroll
    for (int j = 0; j < 4; ++j) {
        const int row = ot * 16 + 4 * j + srow;
        wo[j] = row * 64 + (((scol * 2) ^ ((row & 7) << 4)) >> 1);
    }

    const int q = (lr & 7) << 4;
    int ro[4][2];
    #pragma unroll
    for (int mt = 0; mt < 4; ++mt)
        #pragma unroll
        for (int ss = 0; ss < 2; ++ss)
            ro[mt][ss] = (mt * 16 + lr) * 64 + (((ss * 64 + lg * 16) ^ q) >> 1);

    const __bf16* yb0 = Yf + (size_t)r * (DO_ * N_) + (size_t)kh * 64 * 2048
                           + (size_t)ot * 512 + (size_t)l * 8;

    f32x4 acc[4];
    #pragma unroll
    for (int mt = 0; mt < 4; ++mt) acc[mt] = (f32x4)0.0f;

#define LOADRG(dst, c) {                                                   \
        _Pragma("unroll")                                                  \
        for (int j = 0; j < 4; ++j)                                        \
            dst[j] = *(const f32x4*)(Abl + (size_t)(4 * j) * N_ + (c) * 64); \
    }
#define YLOAD(dst, c) {                                                    \
        dst[0] = *(const bf16x8*)(yb0 + (size_t)((c) * 2 + 0) * 2048);     \
        dst[1] = *(const bf16x8*)(yb0 + (size_t)((c) * 2 + 1) * 2048);     \
    }
#define STAGE(src, par) {                                                  \
        __bf16* ab = &abuf[kh][par][0];                                    \
        _Pragma("unroll")                                                  \
        for (int j = 0; j < 4; ++j) {                                      \
            bf16x4 cv;                                                     \
            cv[0] = (__bf16)src[j][0]; cv[1] = (__bf16)src[j][1];          \
            cv[2] = (__bf16)src[j][2]; cv[3] = (__bf16)src[j][3];          \
            *(bf16x4*)&ab[wo[j]] = cv;                                     \
        }                                                                  \
    }
#define BODY(yfr, par) {                                                   \
        const __bf16* abr = &abuf[kh][par][0];                             \
        _Pragma("unroll")                                                  \
        for (int ss = 0; ss < 2; ++ss) {                                   \
            _Pragma("unroll")                                              \
            for (int mt = 0; mt < 4; ++mt) {                               \
                bf16x8 af = *(const bf16x8*)&abr[ro[mt][ss]];              \
                acc[mt] = __builtin_amdgcn_mfma_f32_16x16x32_bf16(af, yfr[ss], acc[mt], 0, 0, 0); \
            }                                                              \
        }                                                                  \
    }
#define LDSBAR() {                                                         \
        asm volatile("s_waitcnt lgkmcnt(0)" ::: "memory");                 \
        __builtin_amdgcn_s_barrier();                                      \
        __builtin_amdgcn_sched_barrier(0);                                 \
    }

    f32x4 rgA[4], rgB[4];
    bf16x8 yA[2], yB[2];
    LOADRG(rgA, 0);
    LOADRG(rgB, 1);
    YLOAD(yA, 0);

    for (int c = 0; c < 32; c += 2) {
        STAGE(rgA, 0);
        if (c + 2 < 32) LOADRG(rgA, c + 2);
        YLOAD(yB, c + 1);
        LDSBAR();
        BODY(yA, 0);
        STAGE(rgB, 1);
        if (c + 3 < 32) LOADRG(rgB, c + 3);
        if (c + 2 < 32) YLOAD(yA, c + 2);
        LDSBAR();
        BODY(yB, 1);
    }

#undef LOADRG
#undef YLOAD
#undef STAGE
#undef BODY
#undef LDSBAR

    #pragma unroll
    for (int mt = 0; mt < 4; ++mt)
        #pragma unroll
        for (int i = 0; i < 4; ++i)
            red[w][mt * 16 + lg * 4 + i][lr] = acc[mt][i];
    __syncthreads();

    const float p0 = *p0p;
    #pragma unroll
    for (int idx = tid; idx < 1024; idx += 512) {
        const int n  = idx >> 4;
        const int oq = idx & 15;
        const int t2 = oq >> 2;
        const int oo = (oq & 3) * 4;
        f32x4 s4 = *(const f32x4*)&red[t2][n][oo] + *(const f32x4*)&red[t2 + 4][n][oo];
        const int o = t2 * 16 + oo;
        f32x4 uv;
        #pragma unroll
        for (int j = 0; j < 4; ++j) {
            const float v = s4[j] + fcb[r * DO_ + o + j];
            uv[j] = v >= 0.f ? v : p0 * v;
        }
        *(f32x4*)&U[((size_t)r * N_ + n0 + n) * DO_ + o] = uv;
    }
}

// ---------------------------------------------------------------------------
// k_conv: h = prelu(conv_w @ u + conv_b)
// ---------------------------------------------------------------------------
__global__ __launch_bounds__(256) void k_conv(const float* __restrict__ U,
                                              const float* __restrict__ cw,
                                              const float* __restrict__ cb,
                                              const float* __restrict__ p1p,
                                              float* __restrict__ H)
{
    const size_t t = (size_t)blockIdx.x * 256 + threadIdx.x;
    const size_t base = t * 4;
    const size_t SL = (size_t)N_ * DO_;  // 262144

    f32x4 u0 = *(const f32x4*)&U[base];
    f32x4 u1 = *(const f32x4*)&U[base + SL];
    f32x4 u2 = *(const f32x4*)&U[base + 2 * SL];
    f32x4 u3 = *(const f32x4*)&U[base + 3 * SL];
    const float p1 = *p1p;

    #pragma unroll
    for (int qq = 0; qq < 4; ++qq) {
        f32x4 hv = cw[qq * 4 + 0] * u0 + cw[qq * 4 + 1] * u1 +
                   cw[qq * 4 + 2] * u2 + cw[qq * 4 + 3] * u3;
        const float bq = cb[qq];
        f32x4 ho;
        #pragma unroll
        for (int j = 0; j < 4; ++j) {
            const float v = hv[j] + bq;
            ho[j] = v >= 0.f ? v : p1 * v;
        }
        *(f32x4*)&H[qq * SL + base] = ho;
    }
}

extern "C" void kernel_launch(void* const* d_in, const int* in_sizes, int n_in,
                              void* d_out, int out_size, void* d_ws, size_t ws_size,
                              hipStream_t stream)
{
    const float* theta = (const float*)d_in[0];
    const float* tt    = (const float*)d_in[1];
    const float* a     = (const float*)d_in[2];
    const float* x     = (const float*)d_in[3];
    const float* fcw   = (const float*)d_in[4];
    const float* fcb   = (const float*)d_in[5];
    const float* cw    = (const float*)d_in[6];
    const float* cb    = (const float*)d_in[7];
    const float* p0    = (const float*)d_in[8];
    const float* p1    = (const float*)d_in[9];

    float* out = (float*)d_out;
    float* H = out;                              // output 0: h  [R,N,DO]
    float* U = out + (size_t)R_ * N_ * DO_;      // output 1: u  [R,N,DO]

    const size_t ybytes = (size_t)R_ * DO_ * N_ * sizeof(__bf16);
    __bf16* Y = (ws_size >= ybytes) ? (__bf16*)d_ws : (__bf16*)H;

    k_prep<<<dim3(256), dim3(256), 0, stream>>>(theta, tt, x, fcw, Y);
    k_diff<<<dim3(256), dim3(512), 0, stream>>>(a, Y, fcb, p0, U);
    k_conv<<<dim3(256), dim3(256), 0, stream>>>(U, cw, cb, p1, H);
}